// Round 7
// baseline (359.927 us; speedup 1.0000x reference)
//
#include <hip/hip_runtime.h>
#include <hip/hip_fp16.h>

#define N_NODES 100000
#define N_EDGES 1600000
#define DIM 64
#define NB1 391                 // ceil(N_NODES/256)
#define NGROUPS (N_NODES / 4)   // 25000
#define NBLK_GM 1536            // persistent blocks for gather_mlp
#define CSTRIDE 100096          // per-copy counts stride (ints)
#define E4 (N_EDGES / 4)        // 400000
#define E4BLK 1563              // ceil(E4/256)

// ---------------- workspace layout (int units), total ~18.5 MB ----------------
#define OFF_COUNTS8 0           // 8 * CSTRIDE = 800768
#define OFF_SOUT    800768      // 65 floats + done counter at +72
#define OFF_TOT     800848      // 100096
#define OFF_OFFSETS 900944      // 100001
#define OFF_BSUMS   1000960     // 512
#define OFF_CSR     1001472     // 1600000
#define OFF_RANK8   2601472     // 400000
#define OFF_Y8      3001472     // 1600000 ints (fp8-e5m2 x rows, 64 B/row)

// ---- fp8 e5m2 via fp16-byte trick (encode: RN to top byte of half) ----
__device__ __forceinline__ unsigned enc8(float f) {
    __half h = __float2half_rn(f);
    unsigned hb = (unsigned)__half_as_ushort(h);
    return ((hb + 0x80u) >> 8) & 0xFFu;
}

// accumulate 16 fp8 values (one uint4) into acc[0..15]
__device__ __forceinline__ void unpack16(uint4 rr, float* acc) {
    const unsigned w[4] = {rr.x, rr.y, rr.z, rr.w};
    #pragma unroll
    for (int wi = 0; wi < 4; ++wi) {
        unsigned he = (w[wi] & 0x00FF00FFu) << 8;   // half2: (b0<<8, b2<<8)
        unsigned ho =  w[wi] & 0xFF00FF00u;         // half2: (b1<<8, b3<<8)
        float2 fe = __half22float2(*(__half2*)&he);
        float2 fo = __half22float2(*(__half2*)&ho);
        acc[wi * 4 + 0] += fe.x;
        acc[wi * 4 + 1] += fo.x;
        acc[wi * 4 + 2] += fe.y;
        acc[wi * 4 + 3] += fo.y;
    }
}

// ---------------------------------------------------------------------------
// K0: convert x->fp8  +  XCD-private histogram of dst with rank capture
// ---------------------------------------------------------------------------
__global__ __launch_bounds__(256) void convert_hist_kernel(
    const float* __restrict__ x, unsigned* __restrict__ y8,
    const int* __restrict__ dst, int* __restrict__ counts8,
    unsigned* __restrict__ rank8)
{
    int i = blockIdx.x * 256 + threadIdx.x;
    if (i < N_NODES * DIM / 4) {
        float4 v = ((const float4*)x)[i];
        y8[i] = enc8(v.x) | (enc8(v.y) << 8) | (enc8(v.z) << 16) | (enc8(v.w) << 24);
    }
    if (i < E4) {
        int4 d = ((const int4*)dst)[i];
        int* cnt = counts8 + (blockIdx.x & 7) * CSTRIDE;
        unsigned r0 = (unsigned)atomicAdd(&cnt[d.x], 1);
        unsigned r1 = (unsigned)atomicAdd(&cnt[d.y], 1);
        unsigned r2 = (unsigned)atomicAdd(&cnt[d.z], 1);
        unsigned r3 = (unsigned)atomicAdd(&cnt[d.w], 1);
        rank8[i] = r0 | (r1 << 8) | (r2 << 16) | (r3 << 24);
    }
}

// ---------------------------------------------------------------------------
// K1: per-node 8-copy exclusive prefix (in place) + total + per-block sums
// ---------------------------------------------------------------------------
__global__ __launch_bounds__(256) void colsum_blocksum_kernel(
    int* __restrict__ counts8, int* __restrict__ tot, int* __restrict__ bsums)
{
    __shared__ int s[256];
    int t = threadIdx.x;
    int idx = blockIdx.x * 256 + t;
    int run = 0;
    if (idx < N_NODES) {
        #pragma unroll
        for (int k = 0; k < 8; ++k) {
            int v = counts8[k * CSTRIDE + idx];
            counts8[k * CSTRIDE + idx] = run;
            run += v;
        }
        tot[idx] = run;
    }
    s[t] = (idx < N_NODES) ? run : 0;
    __syncthreads();
    for (int d = 128; d > 0; d >>= 1) {
        if (t < d) s[t] += s[t + d];
        __syncthreads();
    }
    if (t == 0) bsums[blockIdx.x] = s[0];
}

// ---------------------------------------------------------------------------
// K2: offsets — block base via masked reduction of UNSCANNED bsums (no
// separate scan launch), then per-block node scan; fold base into counts8.
// ---------------------------------------------------------------------------
__global__ __launch_bounds__(256) void offsets_kernel(
    const int* __restrict__ tot, const int* __restrict__ bsums,
    int* __restrict__ offsets, int* __restrict__ counts8)
{
    __shared__ int s[256];
    __shared__ int base_sh;
    const int t = threadIdx.x;
    const int bid = blockIdx.x;

    int contrib = 0;
    if (t < bid) contrib += bsums[t];
    if (t + 256 < bid) contrib += bsums[t + 256];
    s[t] = contrib;
    __syncthreads();
    for (int d = 128; d > 0; d >>= 1) {
        if (t < d) s[t] += s[t + d];
        __syncthreads();
    }
    if (t == 0) base_sh = s[0];
    __syncthreads();
    const int base = base_sh;
    __syncthreads();

    int idx = bid * 256 + t;
    int c = (idx < N_NODES) ? tot[idx] : 0;
    s[t] = c;
    __syncthreads();
    for (int d = 1; d < 256; d <<= 1) {
        int add = (t >= d) ? s[t - d] : 0;
        __syncthreads();
        s[t] += add;
        __syncthreads();
    }
    int excl = (t == 0) ? 0 : s[t - 1];
    int off = base + excl;
    if (idx < N_NODES) {
        offsets[idx] = off;
        #pragma unroll
        for (int k = 0; k < 8; ++k)
            counts8[k * CSTRIDE + idx] += off;
    }
    if (idx == 0) offsets[N_NODES] = N_EDGES;
}

// ---------------------------------------------------------------------------
// K3: fill CSR — zero atomics (base + captured rank)
// ---------------------------------------------------------------------------
__global__ __launch_bounds__(256) void fill_kernel(
    const int* __restrict__ src, const int* __restrict__ dst,
    const int* __restrict__ counts8, const unsigned* __restrict__ rank8,
    int* __restrict__ csr)
{
    int e4 = blockIdx.x * 256 + threadIdx.x;
    if (e4 < E4) {
        int4 s = ((const int4*)src)[e4];
        int4 d = ((const int4*)dst)[e4];
        unsigned rp = rank8[e4];
        const int* base = counts8 + (((unsigned)e4 >> 8) & 7) * CSTRIDE;
        csr[base[d.x] + (int)(rp & 255u)]         = s.x;
        csr[base[d.y] + (int)((rp >> 8) & 255u)]  = s.y;
        csr[base[d.z] + (int)((rp >> 16) & 255u)] = s.z;
        csr[base[d.w] + (int)((rp >> 24) & 255u)] = s.w;
    }
}

// ---------------------------------------------------------------------------
// K4: fused fp8 gather + layer-1 matvec + weighted reduction + finalize.
// Chunk = 16 edges per 1KB instruction (4 lanes/edge, 16B each).
// slot16 = lane>>2 (edge in chunk), q = lane&3 (column quad 16q..16q+15).
// Butterfly over slot bits (masks 4,8,16,32). Last block runs finalize.
// ---------------------------------------------------------------------------
__global__ __launch_bounds__(256, 5) void gather_mlp_kernel(
    const float* __restrict__ x,
    const unsigned* __restrict__ y8,
    const int* __restrict__ offsets,
    const int* __restrict__ csr,
    const float* __restrict__ weights,
    const float* __restrict__ W1,
    const float* __restrict__ b1,
    const float* __restrict__ W2,
    const float* __restrict__ b2,
    float* __restrict__ sout,
    int* __restrict__ done,
    float* __restrict__ out)
{
    __shared__ float W1s[DIM * DIM];      // 16 KB
    __shared__ float vbuf[4][4][DIM];     // 4 KB
    __shared__ float sred[4][DIM];        // 1 KB
    __shared__ int islast;

    const int tid  = threadIdx.x;
    const int lane = tid & 63;
    const int wave = tid >> 6;
    const int slot16 = lane >> 2;         // 0..15
    const int q      = lane & 3;          // 0..3

    if (tid == 0) islast = 0;
    for (int i = tid; i < DIM * DIM; i += 256) W1s[i] = W1[i];
    __syncthreads();

    const float bias = b1[lane];
    float sacc  = 0.f;
    float swacc = 0.f;

    const uint4* yrows = (const uint4*)y8;   // 4 uint4 per 64-B row

    for (int g = blockIdx.x * 4 + wave; g < NGROUPS; g += NBLK_GM * 4) {
        const int i0 = g * 4;

        int off_l = offsets[i0 + (lane < 5 ? lane : 4)];
        int bg[4], dd[4];
        #pragma unroll
        for (int n = 0; n < 4; ++n) {
            int b = __builtin_amdgcn_readfirstlane(__shfl(off_l, n));
            int e = __builtin_amdgcn_readfirstlane(__shfl(off_l, n + 1));
            bg[n] = b; dd[n] = e - b;
        }

        // Phase A: index loads (covers first 64 edges) + self terms
        int idxv[4];
        float selfv[4];
        #pragma unroll
        for (int n = 0; n < 4; ++n)
            idxv[n] = (lane < dd[n]) ? csr[bg[n] + lane] : 0;
        #pragma unroll
        for (int n = 0; n < 4; ++n)
            selfv[n] = x[(size_t)(i0 + n) * DIM + lane];

        // Phase B: chunks c=0,1 (deg<=32 common path), 4 nodes
        uint4 r[4][2];
        #pragma unroll
        for (int n = 0; n < 4; ++n) {
            #pragma unroll
            for (int c = 0; c < 2; ++c) {
                r[n][c] = make_uint4(0u, 0u, 0u, 0u);
                if (c * 16 < dd[n]) {                 // wave-uniform
                    const int e = c * 16 + slot16;    // <= 31
                    const int sI = __shfl(idxv[n], e);
                    uint4 rr = yrows[(size_t)sI * 4 + q];
                    if (e < dd[n]) r[n][c] = rr;      // tail -> 0
                }
            }
        }

        // Phase C: unpack + tails + butterfly + store
        #pragma unroll
        for (int n = 0; n < 4; ++n) {
            float acc[16];
            #pragma unroll
            for (int i = 0; i < 16; ++i) acc[i] = 0.f;
            unpack16(r[n][0], acc);
            unpack16(r[n][1], acc);

            if (dd[n] > 32) {
                const int dcap = dd[n] <= 64 ? dd[n] : 64;
                #pragma unroll
                for (int c = 2; c < 4; ++c) {
                    if (c * 16 < dcap) {
                        const int e = c * 16 + slot16;
                        const int sI = __shfl(idxv[n], e);
                        if (e < dcap) {
                            uint4 rr = yrows[(size_t)sI * 4 + q];
                            unpack16(rr, acc);
                        }
                    }
                }
                if (dd[n] > 64) {                     // essentially never
                    for (int b0i = 64; b0i < dd[n]; b0i += 64) {
                        int rem = dd[n] - b0i; if (rem > 64) rem = 64;
                        int idx2 = (lane < rem) ? csr[bg[n] + b0i + lane] : 0;
                        for (int c = 0; c * 16 < rem; ++c) {
                            const int e = c * 16 + slot16;
                            const int sI = __shfl(idx2, e);
                            if (e < rem) {
                                uint4 rr = yrows[(size_t)sI * 4 + q];
                                unpack16(rr, acc);
                            }
                        }
                    }
                }
            }

            #pragma unroll
            for (int m = 4; m <= 32; m <<= 1) {
                #pragma unroll
                for (int i = 0; i < 16; ++i)
                    acc[i] += __shfl_xor(acc[i], m);
            }
            if (lane < 4) {
                #pragma unroll
                for (int ii = 0; ii < 4; ++ii)
                    *(float4*)&vbuf[wave][n][lane * 16 + ii * 4] =
                        make_float4(acc[ii * 4 + 0], acc[ii * 4 + 1],
                                    acc[ii * 4 + 2], acc[ii * 4 + 3]);
            }
            vbuf[wave][n][lane] += selfv[n];   // same-wave LDS RMW
        }

        // MLP layer 1 + weighted accumulation
        float a0 = bias, a1 = bias, a2 = bias, a3 = bias;
        #pragma unroll
        for (int k = 0; k < DIM; k += 4) {
            float4 q0 = *(const float4*)&vbuf[wave][0][k];
            float4 q1 = *(const float4*)&vbuf[wave][1][k];
            float4 q2 = *(const float4*)&vbuf[wave][2][k];
            float4 q3 = *(const float4*)&vbuf[wave][3][k];
            float w0 = W1s[(k + 0) * DIM + lane];
            float w1 = W1s[(k + 1) * DIM + lane];
            float w2 = W1s[(k + 2) * DIM + lane];
            float w3 = W1s[(k + 3) * DIM + lane];
            a0 = fmaf(q0.x, w0, a0); a0 = fmaf(q0.y, w1, a0);
            a0 = fmaf(q0.z, w2, a0); a0 = fmaf(q0.w, w3, a0);
            a1 = fmaf(q1.x, w0, a1); a1 = fmaf(q1.y, w1, a1);
            a1 = fmaf(q1.z, w2, a1); a1 = fmaf(q1.w, w3, a1);
            a2 = fmaf(q2.x, w0, a2); a2 = fmaf(q2.y, w1, a2);
            a2 = fmaf(q2.z, w2, a2); a2 = fmaf(q2.w, w3, a2);
            a3 = fmaf(q3.x, w0, a3); a3 = fmaf(q3.y, w1, a3);
            a3 = fmaf(q3.z, w2, a3); a3 = fmaf(q3.w, w3, a3);
        }

        const float wt0 = weights[i0 + 0];
        const float wt1 = weights[i0 + 1];
        const float wt2 = weights[i0 + 2];
        const float wt3 = weights[i0 + 3];
        sacc = fmaf(fmaxf(a0, 0.f), wt0, sacc);
        sacc = fmaf(fmaxf(a1, 0.f), wt1, sacc);
        sacc = fmaf(fmaxf(a2, 0.f), wt2, sacc);
        sacc = fmaf(fmaxf(a3, 0.f), wt3, sacc);
        if (lane == 0) swacc += wt0 + wt1 + wt2 + wt3;
    }

    sred[wave][lane] = sacc;
    __syncthreads();
    if (wave == 0) {
        float t = sred[0][lane] + sred[1][lane] + sred[2][lane] + sred[3][lane];
        atomicAdd(&sout[lane], t);
    }
    if (lane == 0) atomicAdd(&sout[DIM], swacc);

    // ---- fused finalize: last block to finish computes the output ----
    __syncthreads();                       // drain this block's atomics
    if (tid == 0) {
        __threadfence();
        int prev = atomicAdd(done, 1);
        islast = (prev == NBLK_GM - 1) ? 1 : 0;
    }
    __syncthreads();
    if (islast && tid < DIM) {
        __threadfence();
        const int j = tid;
        const float sw = sout[DIM];
        float acc = sw * b2[j];
        #pragma unroll
        for (int k = 0; k < DIM; ++k)
            acc = fmaf(sout[k], W2[k * DIM + j], acc);
        out[j] = acc;
    }
}

extern "C" void kernel_launch(void* const* d_in, const int* in_sizes, int n_in,
                              void* d_out, int out_size, void* d_ws, size_t ws_size,
                              hipStream_t stream)
{
    const float* x       = (const float*)d_in[0];
    const int*   ei      = (const int*)d_in[1];
    const float* weights = (const float*)d_in[2];
    const float* W1      = (const float*)d_in[3];
    const float* b1      = (const float*)d_in[4];
    const float* W2      = (const float*)d_in[5];
    const float* b2      = (const float*)d_in[6];
    float* out = (float*)d_out;

    const int* src = ei;
    const int* dst = ei + N_EDGES;

    int*      wsI     = (int*)d_ws;
    int*      counts8 = wsI + OFF_COUNTS8;
    float*    soutF   = (float*)(wsI + OFF_SOUT);
    int*      done    = wsI + OFF_SOUT + 72;
    int*      tot     = wsI + OFF_TOT;
    int*      offsets = wsI + OFF_OFFSETS;
    int*      bsums   = wsI + OFF_BSUMS;
    int*      csr     = wsI + OFF_CSR;
    unsigned* rank8   = (unsigned*)(wsI + OFF_RANK8);
    unsigned* y8      = (unsigned*)(wsI + OFF_Y8);

    // zero counts8 (3.2 MB) + sout + done counter in one memset
    hipMemsetAsync(d_ws, 0, (size_t)(OFF_SOUT + 80) * sizeof(int), stream);

    convert_hist_kernel   <<<(N_NODES * DIM / 4 + 255) / 256, 256, 0, stream>>>(x, y8, dst, counts8, rank8);
    colsum_blocksum_kernel<<<NB1,    256, 0, stream>>>(counts8, tot, bsums);
    offsets_kernel        <<<NB1,    256, 0, stream>>>(tot, bsums, offsets, counts8);
    fill_kernel           <<<E4BLK,  256, 0, stream>>>(src, dst, counts8, rank8, csr);
    gather_mlp_kernel     <<<NBLK_GM, 256, 0, stream>>>(x, y8, offsets, csr, weights, W1, b1, W2, b2, soutF, done, out);
}

// Round 8
// 305.649 us; speedup vs baseline: 1.1776x; 1.1776x over previous
//
#include <hip/hip_runtime.h>
#include <hip/hip_bf16.h>

#define N_NODES 100000
#define N_EDGES 1600000
#define DIM 64
#define NB1 391                 // ceil(N_NODES/256)
#define NGROUPS (N_NODES / 4)   // 25000
#define NBLK_GM 1792            // 7 blocks/CU (LDS limit), persistent
#define CSTRIDE 100096          // per-copy counts stride (ints)
#define E4 (N_EDGES / 4)        // 400000
#define E4BLK 1563              // ceil(E4/256)

// ---------------- workspace layout (int units) ----------------
#define OFF_COUNTS8 0           // 8 * CSTRIDE = 800768
#define OFF_SOUT    800768      // 65 floats
#define OFF_TOT     800848      // 100096
#define OFF_OFFSETS 900944      // 100001
#define OFF_BSUMS   1000960     // 512
#define OFF_CSR     1001472     // 1600000
#define OFF_RANK8   2601472     // 400000
#define OFF_Y16     3001472     // 3200000 ints (bf16 x rows, 128 B/row)

__device__ __forceinline__ float blo(unsigned u) { return __uint_as_float(u << 16); }
__device__ __forceinline__ float bhi(unsigned u) { return __uint_as_float(u & 0xffff0000u); }

// ---------------------------------------------------------------------------
// K0: convert x->bf16  +  XCD-private histogram of dst with rank capture
// ---------------------------------------------------------------------------
__global__ __launch_bounds__(256) void convert_hist_kernel(
    const float* __restrict__ x, unsigned* __restrict__ y,
    const int* __restrict__ dst, int* __restrict__ counts8,
    unsigned* __restrict__ rank8)
{
    int i = blockIdx.x * 256 + threadIdx.x;
    if (i < N_NODES * DIM / 4) {
        float4 v = ((const float4*)x)[i];
        __hip_bfloat162 p0 = __float22bfloat162_rn(make_float2(v.x, v.y));
        __hip_bfloat162 p1 = __float22bfloat162_rn(make_float2(v.z, v.w));
        uint2 o;
        o.x = *reinterpret_cast<unsigned*>(&p0);
        o.y = *reinterpret_cast<unsigned*>(&p1);
        ((uint2*)y)[i] = o;
    }
    if (i < E4) {
        int4 d = ((const int4*)dst)[i];
        int* cnt = counts8 + (blockIdx.x & 7) * CSTRIDE;
        unsigned r0 = (unsigned)atomicAdd(&cnt[d.x], 1);
        unsigned r1 = (unsigned)atomicAdd(&cnt[d.y], 1);
        unsigned r2 = (unsigned)atomicAdd(&cnt[d.z], 1);
        unsigned r3 = (unsigned)atomicAdd(&cnt[d.w], 1);
        rank8[i] = r0 | (r1 << 8) | (r2 << 16) | (r3 << 24);   // ranks < 256
    }
}

// ---------------------------------------------------------------------------
// K1: per-node 8-copy exclusive prefix (in place) + total + per-block sums
// ---------------------------------------------------------------------------
__global__ __launch_bounds__(256) void colsum_blocksum_kernel(
    int* __restrict__ counts8, int* __restrict__ tot, int* __restrict__ bsums)
{
    __shared__ int s[256];
    int t = threadIdx.x;
    int idx = blockIdx.x * 256 + t;
    int run = 0;
    if (idx < N_NODES) {
        #pragma unroll
        for (int k = 0; k < 8; ++k) {
            int v = counts8[k * CSTRIDE + idx];
            counts8[k * CSTRIDE + idx] = run;
            run += v;
        }
        tot[idx] = run;
    }
    s[t] = (idx < N_NODES) ? run : 0;
    __syncthreads();
    for (int d = 128; d > 0; d >>= 1) {
        if (t < d) s[t] += s[t + d];
        __syncthreads();
    }
    if (t == 0) bsums[blockIdx.x] = s[0];
}

// ---------------------------------------------------------------------------
// K2: offsets — block base via masked reduction of UNSCANNED bsums (fused
// scan, no separate launch), then per-block node scan; fold into counts8.
// ---------------------------------------------------------------------------
__global__ __launch_bounds__(256) void offsets_kernel(
    const int* __restrict__ tot, const int* __restrict__ bsums,
    int* __restrict__ offsets, int* __restrict__ counts8)
{
    __shared__ int s[256];
    __shared__ int base_sh;
    const int t = threadIdx.x;
    const int bid = blockIdx.x;

    int contrib = 0;
    if (t < bid) contrib += bsums[t];
    if (t + 256 < bid) contrib += bsums[t + 256];
    s[t] = contrib;
    __syncthreads();
    for (int d = 128; d > 0; d >>= 1) {
        if (t < d) s[t] += s[t + d];
        __syncthreads();
    }
    if (t == 0) base_sh = s[0];
    __syncthreads();
    const int base = base_sh;
    __syncthreads();

    int idx = bid * 256 + t;
    int c = (idx < N_NODES) ? tot[idx] : 0;
    s[t] = c;
    __syncthreads();
    for (int d = 1; d < 256; d <<= 1) {
        int add = (t >= d) ? s[t - d] : 0;
        __syncthreads();
        s[t] += add;
        __syncthreads();
    }
    int excl = (t == 0) ? 0 : s[t - 1];
    int off = base + excl;
    if (idx < N_NODES) {
        offsets[idx] = off;
        #pragma unroll
        for (int k = 0; k < 8; ++k)
            counts8[k * CSTRIDE + idx] += off;
    }
    if (idx == 0) offsets[N_NODES] = N_EDGES;
}

// ---------------------------------------------------------------------------
// K3: fill CSR — zero atomics (base + captured rank)
// ---------------------------------------------------------------------------
__global__ __launch_bounds__(256) void fill_kernel(
    const int* __restrict__ src, const int* __restrict__ dst,
    const int* __restrict__ counts8, const unsigned* __restrict__ rank8,
    int* __restrict__ csr)
{
    int e4 = blockIdx.x * 256 + threadIdx.x;
    if (e4 < E4) {
        int4 s = ((const int4*)src)[e4];
        int4 d = ((const int4*)dst)[e4];
        unsigned rp = rank8[e4];
        const int* base = counts8 + (((unsigned)e4 >> 8) & 7) * CSTRIDE;
        csr[base[d.x] + (int)(rp & 255u)]         = s.x;
        csr[base[d.y] + (int)((rp >> 8) & 255u)]  = s.y;
        csr[base[d.z] + (int)((rp >> 16) & 255u)] = s.z;
        csr[base[d.w] + (int)((rp >> 24) & 255u)] = s.w;
    }
}

// ---------------------------------------------------------------------------
// K4: fused bf16 gather + layer-1 matvec + weighted reduction.
// Software-pipelined across groups: next group's offsets+index+self loads
// issue before the current group's unpack/MLP, so chunk loads start
// immediately at the next iteration.
// ---------------------------------------------------------------------------
__global__ __launch_bounds__(256) void gather_mlp_kernel(
    const float* __restrict__ x,
    const unsigned* __restrict__ y16,
    const int* __restrict__ offsets,
    const int* __restrict__ csr,
    const float* __restrict__ weights,
    const float* __restrict__ W1,
    const float* __restrict__ b1,
    float* __restrict__ sout)
{
    __shared__ float W1s[DIM * DIM];      // 16 KB
    __shared__ float vbuf[4][4][DIM];     // 4 KB
    __shared__ float sred[4][DIM];        // 1 KB

    const int tid  = threadIdx.x;
    const int lane = tid & 63;
    const int wave = tid >> 6;
    const int slot = lane >> 3;           // edge sub-slot 0..7
    const int h    = lane & 7;            // column octet 0..7

    for (int i = tid; i < DIM * DIM; i += 256) W1s[i] = W1[i];
    __syncthreads();

    const float bias = b1[lane];
    float sacc  = 0.f;
    float swacc = 0.f;

    const uint4* yrows = (const uint4*)y16;   // 8 uint4 per 128-B row
    const int oidx = (lane < 5 ? lane : 4);

    int g = blockIdx.x * 4 + wave;
    int bg[4], dd[4], idxv[4];
    float selfv[4];

    if (g < NGROUPS) {
        // preamble: load state for first group
        int off_l = offsets[g * 4 + oidx];
        #pragma unroll
        for (int n = 0; n < 4; ++n) {
            int b = __builtin_amdgcn_readfirstlane(__shfl(off_l, n));
            int e = __builtin_amdgcn_readfirstlane(__shfl(off_l, n + 1));
            bg[n] = b; dd[n] = e - b;
        }
        #pragma unroll
        for (int n = 0; n < 4; ++n)
            idxv[n] = (lane < dd[n]) ? csr[bg[n] + lane] : 0;
        #pragma unroll
        for (int n = 0; n < 4; ++n)
            selfv[n] = x[(size_t)(g * 4 + n) * DIM + lane];
    }

    while (g < NGROUPS) {
        const int i0 = g * 4;

        // --- Phase B: chunk loads for current group (indices already landed)
        uint4 r[4][3];
        #pragma unroll
        for (int n = 0; n < 4; ++n) {
            #pragma unroll
            for (int c = 0; c < 3; ++c) {
                r[n][c] = make_uint4(0u, 0u, 0u, 0u);
                if (c * 8 < dd[n]) {                    // wave-uniform
                    const int e = c * 8 + slot;
                    const int s = __shfl(idxv[n], e);
                    uint4 rr = yrows[(size_t)s * 8 + h];
                    if (e < dd[n]) r[n][c] = rr;        // tail -> 0
                }
            }
        }

        // --- Prefetch next group's offsets/index/self loads ---
        const int gn = g + NBLK_GM * 4;
        int bgn[4], ddn[4], idxn[4];
        float selfn[4];
        if (gn < NGROUPS) {
            int off_ln = offsets[gn * 4 + oidx];
            #pragma unroll
            for (int n = 0; n < 4; ++n) {
                int b = __builtin_amdgcn_readfirstlane(__shfl(off_ln, n));
                int e = __builtin_amdgcn_readfirstlane(__shfl(off_ln, n + 1));
                bgn[n] = b; ddn[n] = e - b;
            }
            #pragma unroll
            for (int n = 0; n < 4; ++n)
                idxn[n] = (lane < ddn[n]) ? csr[bgn[n] + lane] : 0;
            #pragma unroll
            for (int n = 0; n < 4; ++n)
                selfn[n] = x[(size_t)(gn * 4 + n) * DIM + lane];
        }

        // --- Phase C: unpack + tails + butterfly + vbuf store ---
        #pragma unroll
        for (int n = 0; n < 4; ++n) {
            float a0 = 0.f, a1 = 0.f, a2 = 0.f, a3 = 0.f;
            float a4 = 0.f, a5 = 0.f, a6 = 0.f, a7 = 0.f;
            #pragma unroll
            for (int c = 0; c < 3; ++c) {
                uint4 rr = r[n][c];
                a0 += blo(rr.x); a1 += bhi(rr.x);
                a2 += blo(rr.y); a3 += bhi(rr.y);
                a4 += blo(rr.z); a5 += bhi(rr.z);
                a6 += blo(rr.w); a7 += bhi(rr.w);
            }
            if (dd[n] > 24) {
                const int dcap = dd[n] <= 64 ? dd[n] : 64;
                for (int c = 3; c * 8 < dcap; ++c) {     // uniform branch
                    const int e = c * 8 + slot;
                    const int s = __shfl(idxv[n], e < 64 ? e : 0);
                    if (e < dcap) {
                        uint4 rr = yrows[(size_t)s * 8 + h];
                        a0 += blo(rr.x); a1 += bhi(rr.x);
                        a2 += blo(rr.y); a3 += bhi(rr.y);
                        a4 += blo(rr.z); a5 += bhi(rr.z);
                        a6 += blo(rr.w); a7 += bhi(rr.w);
                    }
                }
                if (dd[n] > 64) {                        // essentially never
                    for (int jj = bg[n] + 64; jj < bg[n] + dd[n]; ++jj) {
                        const int s = csr[jj];
                        if (slot == 0) {
                            uint4 rr = yrows[(size_t)s * 8 + h];
                            a0 += blo(rr.x); a1 += bhi(rr.x);
                            a2 += blo(rr.y); a3 += bhi(rr.y);
                            a4 += blo(rr.z); a5 += bhi(rr.z);
                            a6 += blo(rr.w); a7 += bhi(rr.w);
                        }
                    }
                }
            }
            #pragma unroll
            for (int m = 8; m <= 32; m <<= 1) {
                a0 += __shfl_xor(a0, m); a1 += __shfl_xor(a1, m);
                a2 += __shfl_xor(a2, m); a3 += __shfl_xor(a3, m);
                a4 += __shfl_xor(a4, m); a5 += __shfl_xor(a5, m);
                a6 += __shfl_xor(a6, m); a7 += __shfl_xor(a7, m);
            }
            if (lane < 8) {
                *(float4*)&vbuf[wave][n][lane * 8]     = make_float4(a0, a1, a2, a3);
                *(float4*)&vbuf[wave][n][lane * 8 + 4] = make_float4(a4, a5, a6, a7);
            }
            vbuf[wave][n][lane] += selfv[n];   // same-wave LDS RMW, in-order
        }

        // --- MLP layer 1 + weighted accumulation ---
        float a0 = bias, a1 = bias, a2 = bias, a3 = bias;
        #pragma unroll
        for (int k = 0; k < DIM; k += 4) {
            float4 q0 = *(const float4*)&vbuf[wave][0][k];
            float4 q1 = *(const float4*)&vbuf[wave][1][k];
            float4 q2 = *(const float4*)&vbuf[wave][2][k];
            float4 q3 = *(const float4*)&vbuf[wave][3][k];
            float w0 = W1s[(k + 0) * DIM + lane];
            float w1 = W1s[(k + 1) * DIM + lane];
            float w2 = W1s[(k + 2) * DIM + lane];
            float w3 = W1s[(k + 3) * DIM + lane];
            a0 = fmaf(q0.x, w0, a0); a0 = fmaf(q0.y, w1, a0);
            a0 = fmaf(q0.z, w2, a0); a0 = fmaf(q0.w, w3, a0);
            a1 = fmaf(q1.x, w0, a1); a1 = fmaf(q1.y, w1, a1);
            a1 = fmaf(q1.z, w2, a1); a1 = fmaf(q1.w, w3, a1);
            a2 = fmaf(q2.x, w0, a2); a2 = fmaf(q2.y, w1, a2);
            a2 = fmaf(q2.z, w2, a2); a2 = fmaf(q2.w, w3, a2);
            a3 = fmaf(q3.x, w0, a3); a3 = fmaf(q3.y, w1, a3);
            a3 = fmaf(q3.z, w2, a3); a3 = fmaf(q3.w, w3, a3);
        }

        const float wt0 = weights[i0 + 0];
        const float wt1 = weights[i0 + 1];
        const float wt2 = weights[i0 + 2];
        const float wt3 = weights[i0 + 3];
        sacc = fmaf(fmaxf(a0, 0.f), wt0, sacc);
        sacc = fmaf(fmaxf(a1, 0.f), wt1, sacc);
        sacc = fmaf(fmaxf(a2, 0.f), wt2, sacc);
        sacc = fmaf(fmaxf(a3, 0.f), wt3, sacc);
        if (lane == 0) swacc += wt0 + wt1 + wt2 + wt3;

        // --- rotate pipelined state ---
        g = gn;
        #pragma unroll
        for (int n = 0; n < 4; ++n) {
            bg[n] = bgn[n]; dd[n] = ddn[n];
            idxv[n] = idxn[n]; selfv[n] = selfn[n];
        }
    }

    sred[wave][lane] = sacc;
    __syncthreads();
    if (wave == 0) {
        float t = sred[0][lane] + sred[1][lane] + sred[2][lane] + sred[3][lane];
        atomicAdd(&sout[lane], t);
    }
    if (lane == 0) atomicAdd(&sout[DIM], swacc);
}

// ---------------------------------------------------------------------------
// K5: out = s @ W2 + sw * b2
// ---------------------------------------------------------------------------
__global__ void finalize_kernel(
    const float* __restrict__ sout,
    const float* __restrict__ W2,
    const float* __restrict__ b2,
    float* __restrict__ out)
{
    const int j = threadIdx.x;
    const float sw = sout[DIM];
    float acc = sw * b2[j];
    #pragma unroll
    for (int k = 0; k < DIM; ++k)
        acc = fmaf(sout[k], W2[k * DIM + j], acc);
    out[j] = acc;
}

extern "C" void kernel_launch(void* const* d_in, const int* in_sizes, int n_in,
                              void* d_out, int out_size, void* d_ws, size_t ws_size,
                              hipStream_t stream)
{
    const float* x       = (const float*)d_in[0];
    const int*   ei      = (const int*)d_in[1];
    const float* weights = (const float*)d_in[2];
    const float* W1      = (const float*)d_in[3];
    const float* b1      = (const float*)d_in[4];
    const float* W2      = (const float*)d_in[5];
    const float* b2      = (const float*)d_in[6];
    float* out = (float*)d_out;

    const int* src = ei;
    const int* dst = ei + N_EDGES;

    int*      wsI     = (int*)d_ws;
    int*      counts8 = wsI + OFF_COUNTS8;
    float*    soutF   = (float*)(wsI + OFF_SOUT);
    int*      tot     = wsI + OFF_TOT;
    int*      offsets = wsI + OFF_OFFSETS;
    int*      bsums   = wsI + OFF_BSUMS;
    int*      csr     = wsI + OFF_CSR;
    unsigned* rank8   = (unsigned*)(wsI + OFF_RANK8);
    unsigned* y16     = (unsigned*)(wsI + OFF_Y16);

    // zero counts8 (3.2 MB) + sout in one memset
    hipMemsetAsync(d_ws, 0, (size_t)(OFF_SOUT + 80) * sizeof(int), stream);

    convert_hist_kernel   <<<(N_NODES * DIM / 4 + 255) / 256, 256, 0, stream>>>(x, y16, dst, counts8, rank8);
    colsum_blocksum_kernel<<<NB1,    256, 0, stream>>>(counts8, tot, bsums);
    offsets_kernel        <<<NB1,    256, 0, stream>>>(tot, bsums, offsets, counts8);
    fill_kernel           <<<E4BLK,  256, 0, stream>>>(src, dst, counts8, rank8, csr);
    gather_mlp_kernel     <<<NBLK_GM, 256, 0, stream>>>(x, y16, offsets, csr, weights, W1, b1, soutF);
    finalize_kernel       <<<1,       64, 0, stream>>>(soutF, W2, b2, out);
}

// Round 10
// 293.206 us; speedup vs baseline: 1.2276x; 1.0424x over previous
//
#include <hip/hip_runtime.h>
#include <hip/hip_bf16.h>
#include <hip/hip_cooperative_groups.h>

namespace cg = cooperative_groups;

#define N_NODES 100000
#define N_EDGES 1600000
#define DIM 64
#define NB1 391                  // ceil(N_NODES/256)
#define NGROUPS (N_NODES / 4)    // 25000
#define NBLK 1024                // 4 blocks/CU co-resident (coop launch)
#define GSZ (NBLK * 256)
#define CSTRIDE 100096           // per-copy counts stride (ints)
#define E4 (N_EDGES / 4)         // 400000
#define E4BLK 1563
#define ND4 (N_NODES * DIM / 4)  // 1600000
#define NBLK_GM 1536             // fallback gather grid

// ---------------- workspace layout (int units) ----------------
#define OFF_COUNTS8 0            // 8 * CSTRIDE = 800768
#define OFF_SOUT    800768       // 80 (65 floats used)
#define OFF_TOT     800848      // 100096
#define OFF_OFFSETS 900944      // 100001
#define OFF_BSUMS   1000960     // 512
#define OFF_CSR     1001472     // 1600000
#define OFF_RANK8   2601472     // 400000
#define OFF_Y16     3001472     // 3200000 (bf16 x rows, 128 B/row)

__device__ __forceinline__ float blo(unsigned u) { return __uint_as_float(u << 16); }
__device__ __forceinline__ float bhi(unsigned u) { return __uint_as_float(u & 0xffff0000u); }

// ===========================================================================
// Shared device helpers (used by both mega kernel and fallback kernels)
// ===========================================================================
__device__ __forceinline__ void gather_mlp_body(
    const float* __restrict__ x, const unsigned* __restrict__ y16,
    const int* __restrict__ offsets, const int* __restrict__ csr,
    const float* __restrict__ weights, const float* __restrict__ W1,
    const float* __restrict__ b1, float* __restrict__ sout,
    float (*W1s)/*[DIM*DIM]*/, float (*vbuf)[4][DIM], float (*sred)[DIM],
    int gridBlocks, int bid, int tid)
{
    const int lane = tid & 63;
    const int wave = tid >> 6;
    const int slot = lane >> 3;           // edge sub-slot 0..7
    const int h    = lane & 7;            // column octet 0..7

    for (int i = tid; i < DIM * DIM; i += 256) W1s[i] = W1[i];
    __syncthreads();

    const float bias = b1[lane];
    float sacc  = 0.f;
    float swacc = 0.f;

    const uint4* yrows = (const uint4*)y16;   // 8 uint4 per 128-B row

    for (int g = bid * 4 + wave; g < NGROUPS; g += gridBlocks * 4) {
        const int i0 = g * 4;

        int off_l = offsets[i0 + (lane < 5 ? lane : 4)];
        int bg[4], dd[4];
        #pragma unroll
        for (int n = 0; n < 4; ++n) {
            int b = __builtin_amdgcn_readfirstlane(__shfl(off_l, n));
            int e = __builtin_amdgcn_readfirstlane(__shfl(off_l, n + 1));
            bg[n] = b; dd[n] = e - b;
        }

        int idxv[4];
        float selfv[4];
        #pragma unroll
        for (int n = 0; n < 4; ++n)
            idxv[n] = (lane < dd[n]) ? csr[bg[n] + lane] : 0;
        #pragma unroll
        for (int n = 0; n < 4; ++n)
            selfv[n] = x[(size_t)(i0 + n) * DIM + lane];

        uint4 r[4][3];
        #pragma unroll
        for (int n = 0; n < 4; ++n) {
            #pragma unroll
            for (int c = 0; c < 3; ++c) {
                r[n][c] = make_uint4(0u, 0u, 0u, 0u);
                if (c * 8 < dd[n]) {                    // wave-uniform
                    const int e = c * 8 + slot;
                    const int s = __shfl(idxv[n], e);
                    uint4 rr = yrows[(size_t)s * 8 + h];
                    if (e < dd[n]) r[n][c] = rr;        // tail -> 0
                }
            }
        }

        #pragma unroll
        for (int n = 0; n < 4; ++n) {
            float a0 = 0.f, a1 = 0.f, a2 = 0.f, a3 = 0.f;
            float a4 = 0.f, a5 = 0.f, a6 = 0.f, a7 = 0.f;
            #pragma unroll
            for (int c = 0; c < 3; ++c) {
                if (c * 8 < dd[n]) {                    // skip dead chunks
                    uint4 rr = r[n][c];
                    a0 += blo(rr.x); a1 += bhi(rr.x);
                    a2 += blo(rr.y); a3 += bhi(rr.y);
                    a4 += blo(rr.z); a5 += bhi(rr.z);
                    a6 += blo(rr.w); a7 += bhi(rr.w);
                }
            }
            if (dd[n] > 24) {
                const int dcap = dd[n] <= 64 ? dd[n] : 64;
                for (int c = 3; c * 8 < dcap; ++c) {     // uniform branch
                    const int e = c * 8 + slot;
                    const int s = __shfl(idxv[n], e < 64 ? e : 0);
                    if (e < dcap) {
                        uint4 rr = yrows[(size_t)s * 8 + h];
                        a0 += blo(rr.x); a1 += bhi(rr.x);
                        a2 += blo(rr.y); a3 += bhi(rr.y);
                        a4 += blo(rr.z); a5 += bhi(rr.z);
                        a6 += blo(rr.w); a7 += bhi(rr.w);
                    }
                }
                if (dd[n] > 64) {                        // essentially never
                    for (int jj = bg[n] + 64; jj < bg[n] + dd[n]; ++jj) {
                        const int s = csr[jj];
                        if (slot == 0) {
                            uint4 rr = yrows[(size_t)s * 8 + h];
                            a0 += blo(rr.x); a1 += bhi(rr.x);
                            a2 += blo(rr.y); a3 += bhi(rr.y);
                            a4 += blo(rr.z); a5 += bhi(rr.z);
                            a6 += blo(rr.w); a7 += bhi(rr.w);
                        }
                    }
                }
            }
            #pragma unroll
            for (int m = 8; m <= 32; m <<= 1) {
                a0 += __shfl_xor(a0, m); a1 += __shfl_xor(a1, m);
                a2 += __shfl_xor(a2, m); a3 += __shfl_xor(a3, m);
                a4 += __shfl_xor(a4, m); a5 += __shfl_xor(a5, m);
                a6 += __shfl_xor(a6, m); a7 += __shfl_xor(a7, m);
            }
            if (lane < 8) {
                *(float4*)&vbuf[wave][n][lane * 8]     = make_float4(a0, a1, a2, a3);
                *(float4*)&vbuf[wave][n][lane * 8 + 4] = make_float4(a4, a5, a6, a7);
            }
            vbuf[wave][n][lane] += selfv[n];   // same-wave LDS RMW, in-order
        }

        float a0 = bias, a1 = bias, a2 = bias, a3 = bias;
        #pragma unroll
        for (int k = 0; k < DIM; k += 4) {
            float4 q0 = *(const float4*)&vbuf[wave][0][k];
            float4 q1 = *(const float4*)&vbuf[wave][1][k];
            float4 q2 = *(const float4*)&vbuf[wave][2][k];
            float4 q3 = *(const float4*)&vbuf[wave][3][k];
            float w0 = W1s[(k + 0) * DIM + lane];
            float w1 = W1s[(k + 1) * DIM + lane];
            float w2 = W1s[(k + 2) * DIM + lane];
            float w3 = W1s[(k + 3) * DIM + lane];
            a0 = fmaf(q0.x, w0, a0); a0 = fmaf(q0.y, w1, a0);
            a0 = fmaf(q0.z, w2, a0); a0 = fmaf(q0.w, w3, a0);
            a1 = fmaf(q1.x, w0, a1); a1 = fmaf(q1.y, w1, a1);
            a1 = fmaf(q1.z, w2, a1); a1 = fmaf(q1.w, w3, a1);
            a2 = fmaf(q2.x, w0, a2); a2 = fmaf(q2.y, w1, a2);
            a2 = fmaf(q2.z, w2, a2); a2 = fmaf(q2.w, w3, a2);
            a3 = fmaf(q3.x, w0, a3); a3 = fmaf(q3.y, w1, a3);
            a3 = fmaf(q3.z, w2, a3); a3 = fmaf(q3.w, w3, a3);
        }

        const float wt0 = weights[i0 + 0];
        const float wt1 = weights[i0 + 1];
        const float wt2 = weights[i0 + 2];
        const float wt3 = weights[i0 + 3];
        sacc = fmaf(fmaxf(a0, 0.f), wt0, sacc);
        sacc = fmaf(fmaxf(a1, 0.f), wt1, sacc);
        sacc = fmaf(fmaxf(a2, 0.f), wt2, sacc);
        sacc = fmaf(fmaxf(a3, 0.f), wt3, sacc);
        if (lane == 0) swacc += wt0 + wt1 + wt2 + wt3;
    }

    sred[wave][lane] = sacc;
    __syncthreads();
    if (wave == 0) {
        float t = sred[0][lane] + sred[1][lane] + sred[2][lane] + sred[3][lane];
        atomicAdd(&sout[lane], t);
    }
    if (lane == 0) atomicAdd(&sout[DIM], swacc);
}

// ===========================================================================
// Cooperative mega-kernel: 7 phases with grid.sync() boundaries
// ===========================================================================
__global__ __launch_bounds__(256, 4) void mega_kernel(
    const float* __restrict__ x,
    const int* __restrict__ src,
    const int* __restrict__ dst,
    const float* __restrict__ weights,
    const float* __restrict__ W1,
    const float* __restrict__ b1,
    const float* __restrict__ W2,
    const float* __restrict__ b2,
    int* __restrict__ ws,
    float* __restrict__ out)
{
    cg::grid_group grid = cg::this_grid();

    __shared__ float W1s[DIM * DIM];      // 16 KB
    __shared__ float vbuf[4][4][DIM];     // 4 KB
    __shared__ float sred[4][DIM];        // 1 KB
    __shared__ int   sscan[256];          // 1 KB
    __shared__ int   base_sh;

    int*      counts8 = ws + OFF_COUNTS8;
    float*    sout    = (float*)(ws + OFF_SOUT);
    int*      tot     = ws + OFF_TOT;
    int*      offsets = ws + OFF_OFFSETS;
    int*      bsums   = ws + OFF_BSUMS;
    int*      csr     = ws + OFF_CSR;
    unsigned* rank8   = (unsigned*)(ws + OFF_RANK8);
    unsigned* y16     = (unsigned*)(ws + OFF_Y16);

    const int tid  = threadIdx.x;
    const int bid  = blockIdx.x;
    const int gtid = bid * 256 + tid;

    // ---- P0: zero counts8 (+sout) ----
    for (int i = gtid; i < OFF_SOUT + 80; i += GSZ) ws[i] = 0;
    grid.sync();

    // ---- P1: convert + XCD-private hist with rank capture ----
    for (int i = gtid; i < ND4; i += GSZ) {
        float4 v = ((const float4*)x)[i];
        __hip_bfloat162 p0 = __float22bfloat162_rn(make_float2(v.x, v.y));
        __hip_bfloat162 p1 = __float22bfloat162_rn(make_float2(v.z, v.w));
        uint2 o;
        o.x = *reinterpret_cast<unsigned*>(&p0);
        o.y = *reinterpret_cast<unsigned*>(&p1);
        ((uint2*)y16)[i] = o;
    }
    for (int i = gtid; i < E4; i += GSZ) {
        int4 d = ((const int4*)dst)[i];
        // (i>>8)&7 == bid&7 for all grid-stride iters (GSZ/256 = 1024 ≡ 0 mod 8)
        int* cnt = counts8 + (((unsigned)i >> 8) & 7) * CSTRIDE;
        unsigned r0 = (unsigned)atomicAdd(&cnt[d.x], 1);
        unsigned r1 = (unsigned)atomicAdd(&cnt[d.y], 1);
        unsigned r2 = (unsigned)atomicAdd(&cnt[d.z], 1);
        unsigned r3 = (unsigned)atomicAdd(&cnt[d.w], 1);
        rank8[i] = r0 | (r1 << 8) | (r2 << 16) | (r3 << 24);   // ranks < 256
    }
    grid.sync();

    // ---- P2: per-node 8-copy exclusive prefix + total + block sums ----
    if (bid < NB1) {
        int idx = bid * 256 + tid;
        int run = 0;
        if (idx < N_NODES) {
            #pragma unroll
            for (int k = 0; k < 8; ++k) {
                int v = counts8[k * CSTRIDE + idx];
                counts8[k * CSTRIDE + idx] = run;
                run += v;
            }
            tot[idx] = run;
        }
        sscan[tid] = (idx < N_NODES) ? run : 0;
        __syncthreads();
        for (int d = 128; d > 0; d >>= 1) {
            if (tid < d) sscan[tid] += sscan[tid + d];
            __syncthreads();
        }
        if (tid == 0) bsums[bid] = sscan[0];
    }
    grid.sync();

    // ---- P3: offsets (block base from unscanned bsums) + fold into counts8 ----
    if (bid < NB1) {
        int contrib = 0;
        if (tid < bid) contrib += bsums[tid];
        if (tid + 256 < bid) contrib += bsums[tid + 256];
        sscan[tid] = contrib;
        __syncthreads();
        for (int d = 128; d > 0; d >>= 1) {
            if (tid < d) sscan[tid] += sscan[tid + d];
            __syncthreads();
        }
        if (tid == 0) base_sh = sscan[0];
        __syncthreads();
        const int base = base_sh;
        __syncthreads();

        int idx = bid * 256 + tid;
        int c = (idx < N_NODES) ? tot[idx] : 0;
        sscan[tid] = c;
        __syncthreads();
        for (int d = 1; d < 256; d <<= 1) {
            int add = (tid >= d) ? sscan[tid - d] : 0;
            __syncthreads();
            sscan[tid] += add;
            __syncthreads();
        }
        int excl = (tid == 0) ? 0 : sscan[tid - 1];
        int off = base + excl;
        if (idx < N_NODES) {
            offsets[idx] = off;
            #pragma unroll
            for (int k = 0; k < 8; ++k)
                counts8[k * CSTRIDE + idx] += off;
        }
        if (idx == 0) offsets[N_NODES] = N_EDGES;
    }
    grid.sync();

    // ---- P4: fill CSR (zero atomics) ----
    for (int e4 = gtid; e4 < E4; e4 += GSZ) {
        int4 s = ((const int4*)src)[e4];
        int4 d = ((const int4*)dst)[e4];
        unsigned rp = rank8[e4];
        const int* base = counts8 + (((unsigned)e4 >> 8) & 7) * CSTRIDE;
        csr[base[d.x] + (int)(rp & 255u)]         = s.x;
        csr[base[d.y] + (int)((rp >> 8) & 255u)]  = s.y;
        csr[base[d.z] + (int)((rp >> 16) & 255u)] = s.z;
        csr[base[d.w] + (int)((rp >> 24) & 255u)] = s.w;
    }
    grid.sync();

    // ---- P5: gather + layer-1 matvec + weighted reduction ----
    gather_mlp_body(x, y16, offsets, csr, weights, W1, b1, sout,
                    W1s, vbuf, sred, NBLK, bid, tid);
    grid.sync();

    // ---- P6: finalize (block 0): out = s @ W2 + sw * b2 ----
    if (bid == 0 && tid < DIM) {
        const int j = tid;
        const float sw = sout[DIM];
        float acc = sw * b2[j];
        #pragma unroll
        for (int k = 0; k < DIM; ++k)
            acc = fmaf(sout[k], W2[k * DIM + j], acc);
        out[j] = acc;
    }
}

// ===========================================================================
// Fallback multi-kernel path (proven R8 structure)
// ===========================================================================
__global__ __launch_bounds__(256) void convert_hist_kernel(
    const float* __restrict__ x, unsigned* __restrict__ y,
    const int* __restrict__ dst, int* __restrict__ counts8,
    unsigned* __restrict__ rank8)
{
    int i = blockIdx.x * 256 + threadIdx.x;
    if (i < ND4) {
        float4 v = ((const float4*)x)[i];
        __hip_bfloat162 p0 = __float22bfloat162_rn(make_float2(v.x, v.y));
        __hip_bfloat162 p1 = __float22bfloat162_rn(make_float2(v.z, v.w));
        uint2 o;
        o.x = *reinterpret_cast<unsigned*>(&p0);
        o.y = *reinterpret_cast<unsigned*>(&p1);
        ((uint2*)y)[i] = o;
    }
    if (i < E4) {
        int4 d = ((const int4*)dst)[i];
        int* cnt = counts8 + (((unsigned)i >> 8) & 7) * CSTRIDE;
        unsigned r0 = (unsigned)atomicAdd(&cnt[d.x], 1);
        unsigned r1 = (unsigned)atomicAdd(&cnt[d.y], 1);
        unsigned r2 = (unsigned)atomicAdd(&cnt[d.z], 1);
        unsigned r3 = (unsigned)atomicAdd(&cnt[d.w], 1);
        rank8[i] = r0 | (r1 << 8) | (r2 << 16) | (r3 << 24);
    }
}

__global__ __launch_bounds__(256) void colsum_blocksum_kernel(
    int* __restrict__ counts8, int* __restrict__ tot, int* __restrict__ bsums)
{
    __shared__ int s[256];
    int t = threadIdx.x;
    int idx = blockIdx.x * 256 + t;
    int run = 0;
    if (idx < N_NODES) {
        #pragma unroll
        for (int k = 0; k < 8; ++k) {
            int v = counts8[k * CSTRIDE + idx];
            counts8[k * CSTRIDE + idx] = run;
            run += v;
        }
        tot[idx] = run;
    }
    s[t] = (idx < N_NODES) ? run : 0;
    __syncthreads();
    for (int d = 128; d > 0; d >>= 1) {
        if (t < d) s[t] += s[t + d];
        __syncthreads();
    }
    if (t == 0) bsums[blockIdx.x] = s[0];
}

__global__ __launch_bounds__(256) void offsets_kernel(
    const int* __restrict__ tot, const int* __restrict__ bsums,
    int* __restrict__ offsets, int* __restrict__ counts8)
{
    __shared__ int s[256];
    __shared__ int base_sh;
    const int t = threadIdx.x;
    const int bid = blockIdx.x;

    int contrib = 0;
    if (t < bid) contrib += bsums[t];
    if (t + 256 < bid) contrib += bsums[t + 256];
    s[t] = contrib;
    __syncthreads();
    for (int d = 128; d > 0; d >>= 1) {
        if (t < d) s[t] += s[t + d];
        __syncthreads();
    }
    if (t == 0) base_sh = s[0];
    __syncthreads();
    const int base = base_sh;
    __syncthreads();

    int idx = bid * 256 + t;
    int c = (idx < N_NODES) ? tot[idx] : 0;
    s[t] = c;
    __syncthreads();
    for (int d = 1; d < 256; d <<= 1) {
        int add = (t >= d) ? s[t - d] : 0;
        __syncthreads();
        s[t] += add;
        __syncthreads();
    }
    int excl = (t == 0) ? 0 : s[t - 1];
    int off = base + excl;
    if (idx < N_NODES) {
        offsets[idx] = off;
        #pragma unroll
        for (int k = 0; k < 8; ++k)
            counts8[k * CSTRIDE + idx] += off;
    }
    if (idx == 0) offsets[N_NODES] = N_EDGES;
}

__global__ __launch_bounds__(256) void fill_kernel(
    const int* __restrict__ src, const int* __restrict__ dst,
    const int* __restrict__ counts8, const unsigned* __restrict__ rank8,
    int* __restrict__ csr)
{
    int e4 = blockIdx.x * 256 + threadIdx.x;
    if (e4 < E4) {
        int4 s = ((const int4*)src)[e4];
        int4 d = ((const int4*)dst)[e4];
        unsigned rp = rank8[e4];
        const int* base = counts8 + (((unsigned)e4 >> 8) & 7) * CSTRIDE;
        csr[base[d.x] + (int)(rp & 255u)]         = s.x;
        csr[base[d.y] + (int)((rp >> 8) & 255u)]  = s.y;
        csr[base[d.z] + (int)((rp >> 16) & 255u)] = s.z;
        csr[base[d.w] + (int)((rp >> 24) & 255u)] = s.w;
    }
}

__global__ __launch_bounds__(256) void gather_mlp_kernel(
    const float* __restrict__ x, const unsigned* __restrict__ y16,
    const int* __restrict__ offsets, const int* __restrict__ csr,
    const float* __restrict__ weights, const float* __restrict__ W1,
    const float* __restrict__ b1, float* __restrict__ sout)
{
    __shared__ float W1s[DIM * DIM];
    __shared__ float vbuf[4][4][DIM];
    __shared__ float sred[4][DIM];
    gather_mlp_body(x, y16, offsets, csr, weights, W1, b1, sout,
                    W1s, vbuf, sred, NBLK_GM, blockIdx.x, threadIdx.x);
}

__global__ void finalize_kernel(
    const float* __restrict__ sout,
    const float* __restrict__ W2,
    const float* __restrict__ b2,
    float* __restrict__ out)
{
    const int j = threadIdx.x;
    const float sw = sout[DIM];
    float acc = sw * b2[j];
    #pragma unroll
    for (int k = 0; k < DIM; ++k)
        acc = fmaf(sout[k], W2[k * DIM + j], acc);
    out[j] = acc;
}

extern "C" void kernel_launch(void* const* d_in, const int* in_sizes, int n_in,
                              void* d_out, int out_size, void* d_ws, size_t ws_size,
                              hipStream_t stream)
{
    const float* x       = (const float*)d_in[0];
    const int*   ei      = (const int*)d_in[1];
    const float* weights = (const float*)d_in[2];
    const float* W1      = (const float*)d_in[3];
    const float* b1      = (const float*)d_in[4];
    const float* W2      = (const float*)d_in[5];
    const float* b2      = (const float*)d_in[6];
    float* out = (float*)d_out;

    const int* src = ei;
    const int* dst = ei + N_EDGES;
    int* wsI = (int*)d_ws;

    // Host-side capacity check (capture-safe; deterministic every call).
    int maxb = 0;
    hipError_t oe = hipOccupancyMaxActiveBlocksPerMultiprocessor(
        &maxb, (const void*)mega_kernel, 256, 0);
    bool coop_ok = (oe == hipSuccess) && (maxb >= 4);

    if (coop_ok) {
        void* args[] = {
            (void*)&x, (void*)&src, (void*)&dst, (void*)&weights,
            (void*)&W1, (void*)&b1, (void*)&W2, (void*)&b2,
            (void*)&wsI, (void*)&out
        };
        hipLaunchCooperativeKernel((const void*)mega_kernel,
                                   dim3(NBLK), dim3(256), args, 0, stream);
    } else {
        int*      counts8 = wsI + OFF_COUNTS8;
        float*    soutF   = (float*)(wsI + OFF_SOUT);
        int*      tot     = wsI + OFF_TOT;
        int*      offsets = wsI + OFF_OFFSETS;
        int*      bsums   = wsI + OFF_BSUMS;
        int*      csr     = wsI + OFF_CSR;
        unsigned* rank8   = (unsigned*)(wsI + OFF_RANK8);
        unsigned* y16     = (unsigned*)(wsI + OFF_Y16);

        hipMemsetAsync(d_ws, 0, (size_t)(OFF_SOUT + 80) * sizeof(int), stream);
        convert_hist_kernel   <<<(ND4 + 255) / 256, 256, 0, stream>>>(x, y16, dst, counts8, rank8);
        colsum_blocksum_kernel<<<NB1,    256, 0, stream>>>(counts8, tot, bsums);
        offsets_kernel        <<<NB1,    256, 0, stream>>>(tot, bsums, offsets, counts8);
        fill_kernel           <<<E4BLK,  256, 0, stream>>>(src, dst, counts8, rank8, csr);
        gather_mlp_kernel     <<<NBLK_GM, 256, 0, stream>>>(x, y16, offsets, csr, weights, W1, b1, soutF);
        finalize_kernel       <<<1,       64, 0, stream>>>(soutF, W2, b2, out);
    }
}